// Round 8
// baseline (988.338 us; speedup 1.0000x reference)
//
#include <hip/hip_runtime.h>
#include <stdint.h>

// Problem constants (fixed by the reference's setup_inputs)
#define NB 131072
#define ND 384
#define NA 1024
#define NH 512
#define BM 64       // rows of x per compute block
#define CAPG 4096   // global sparse correction-pair capacity

using bf16x8 = __attribute__((ext_vector_type(8))) __bf16;
using f32x16 = __attribute__((ext_vector_type(16))) float;
using f32x4  = __attribute__((ext_vector_type(4))) float;
using i32x4  = __attribute__((ext_vector_type(4))) int;

__device__ __forceinline__ unsigned short f2bf(float f) {
  unsigned int u = __float_as_uint(f);
  u += 0x7fffu + ((u >> 16) & 1u);   // round-to-nearest-even
  return (unsigned short)(u >> 16);
}

// ---------------- prep: normalize anchors -> bf16, MFMA B-fragment order for
// v_mfma_f32_32x32x16_bf16: lane l holds an[cb*32+(l&31)][s*16+(l>>5)*8+j].
__global__ void prep_anchors(const float* __restrict__ anchors,
                             short* __restrict__ an_swz) {
  const int a = blockIdx.x;    // anchor row
  const int l = threadIdx.x;   // 64 lanes
  float v[6];
  float ss = 0.f;
#pragma unroll
  for (int e = 0; e < 6; ++e) {
    v[e] = anchors[a * ND + l + 64 * e];
    ss += v[e] * v[e];
  }
#pragma unroll
  for (int off = 32; off >= 1; off >>= 1) ss += __shfl_xor(ss, off);
  const float rn = 1.0f / fmaxf(sqrtf(ss), 1e-12f);
  const int cb = a >> 5;
#pragma unroll
  for (int e = 0; e < 6; ++e) {
    const int k = l + 64 * e;
    const int s = k >> 4, half = (k >> 3) & 1, j = k & 7;
    const int l2 = (a & 31) + 32 * half;
    an_swz[(cb * 24 + s) * 512 + l2 * 8 + j] = (short)f2bf(v[e] * rn);
  }
}

// ---------------- prep: Vsum[h] = sum_a values[a][h] (two-stage, deterministic)
__global__ void vsum_part(const float* __restrict__ values,
                          float* __restrict__ partial) {
  const int jb = blockIdx.x, t = threadIdx.x;
  for (int hh = t; hh < NH; hh += 256) {
    float s = 0.f;
    for (int a2 = 0; a2 < 32; ++a2) s += values[(jb * 32 + a2) * NH + hh];
    partial[jb * NH + hh] = s;
  }
}

__global__ void vsum_final(const float* __restrict__ partial,
                           float* __restrict__ vsum, int* __restrict__ g_np) {
  const int t = threadIdx.x;
  if (t == 0) *g_np = 0;  // re-zeroed every launch -> deterministic replays
  float s = 0.f;
  for (int j = 0; j < 32; ++j) s += partial[j * NH + t];
  vsum[t] = s;
}

// ---------------- mega kernel: heterogeneous grid, 7-block groups of
// {4 compute, 2 qsims-zero-fill, 1 out-broadcast-fill} so read/write streams
// overlap machine-wide for the whole duration.
// Compute blocks = R1's proven core (8 waves, x->LDS swizzled, wave-owned B
// panel from L2, 2 MFMA per B fragment) with ZERO dense stores: exceptions
// (nonzero bins, ~0 expected) go to a global pair list.
__global__ __launch_bounds__(512, 6) void mega(
    const float* __restrict__ x, const short* __restrict__ an_swz,
    const float* __restrict__ vsum, float* __restrict__ out,
    float* __restrict__ qsims, int* __restrict__ g_np,
    unsigned int* __restrict__ g_pr, float* __restrict__ g_pq) {
  const int grp = blockIdx.x / 7, slot = blockIdx.x % 7;
  const int t = threadIdx.x;

  if (slot >= 4) {
    if (slot < 6) {
      // ---- qsims zero-fill: 1024 blocks x 131072 floats (nt streaming)
      float* dst = qsims + (long)(grp * 2 + (slot - 4)) * 131072;
      const f32x4 z = {0.f, 0.f, 0.f, 0.f};
#pragma unroll
      for (int it = 0; it < 64; ++it)
        __builtin_nontemporal_store(
            z, reinterpret_cast<f32x4*>(dst + it * 2048 + t * 4));
    } else {
      // ---- out broadcast-fill: 512 blocks x 256 rows of vsum/1024
      const long r0 = (long)grp * 256;
      const int hq = (t & 127) * 4, rsub = t >> 7;
      f32x4 b = *reinterpret_cast<const f32x4*>(vsum + hq);
      const float inv = 1.0f / 1024.0f;
      const f32x4 o = {b[0] * inv, b[1] * inv, b[2] * inv, b[3] * inv};
#pragma unroll
      for (int it = 0; it < 64; ++it) {
        const long r = r0 + it * 4 + rsub;
        __builtin_nontemporal_store(
            o, reinterpret_cast<f32x4*>(out + r * NH + hq));
      }
    }
    return;
  }

  // ---- compute block
  __shared__ unsigned char xbuf[BM * 768];  // bf16 [64][384], XOR-swizzled
  __shared__ float rsc[BM];

  const long rowbase = (long)(grp * 4 + slot) * BM;

  {  // stage x tile (coalesced, plain loads)
    const int r = t >> 3, c = t & 7;  // 8 threads per row
    const float* xrow = x + (rowbase + r) * ND;
    float ss = 0.f;
#pragma unroll
    for (int j = 0; j < 6; ++j) {
      const int col0 = c * 8 + j * 64;
      f32x4 v0 = *reinterpret_cast<const f32x4*>(xrow + col0);
      f32x4 v1 = *reinterpret_cast<const f32x4*>(xrow + col0 + 4);
      ss += v0[0] * v0[0] + v0[1] * v0[1] + v0[2] * v0[2] + v0[3] * v0[3];
      ss += v1[0] * v1[0] + v1[1] * v1[1] + v1[2] * v1[2] + v1[3] * v1[3];
      union { unsigned short us[8]; i32x4 q; } pk;
#pragma unroll
      for (int e = 0; e < 4; ++e) {
        pk.us[e] = f2bf(v0[e]);
        pk.us[4 + e] = f2bf(v1[e]);
      }
      // row*768 has bits 0..7 == 0, col0*2 < 768 -> XOR on bits 4..6 is safe
      *reinterpret_cast<i32x4*>(
          xbuf + ((r * 768 + col0 * 2) ^ ((r & 7) << 4))) = pk.q;
    }
    ss += __shfl_xor(ss, 1);
    ss += __shfl_xor(ss, 2);
    ss += __shfl_xor(ss, 4);
    if (c == 0) {
      const float scale = 1.0f / sqrtf((float)ND);
      rsc[r] = scale / fmaxf(sqrtf(ss), 1e-12f);
    }
  }
  __syncthreads();

  const int w = t >> 6, l = t & 63;
  const int lc = l & 31, lh = l >> 5;
  const int swz = (lc & 7) << 4;
  const unsigned char* arow0 = xbuf + 768 * lc;
  const unsigned char* arow1 = xbuf + 768 * (lc + 32);

  for (int chunk = 0; chunk < 4; ++chunk) {
    const int cb = chunk * 8 + w;  // global 32-col anchor block, 0..31
    f32x16 acc0 = {0, 0, 0, 0, 0, 0, 0, 0, 0, 0, 0, 0, 0, 0, 0, 0};
    f32x16 acc1 = {0, 0, 0, 0, 0, 0, 0, 0, 0, 0, 0, 0, 0, 0, 0, 0};
    const short* bptr = an_swz + (cb * 24) * 512 + l * 8;
#pragma unroll
    for (int s = 0; s < 24; ++s) {
      const int off = (s * 32 + lh * 16) ^ swz;
      bf16x8 a0 = *reinterpret_cast<const bf16x8*>(arow0 + off);
      bf16x8 a1 = *reinterpret_cast<const bf16x8*>(arow1 + off);
      bf16x8 bb = *reinterpret_cast<const bf16x8*>(bptr + s * 512);
      acc0 = __builtin_amdgcn_mfma_f32_32x32x16_bf16(a0, bb, acc0, 0, 0, 0);
      acc1 = __builtin_amdgcn_mfma_f32_32x32x16_bf16(a1, bb, acc1, 0, 0, 0);
    }

    // detect nonzero bins only (no dense stores).
    // C/D layout: col=lane&31, row=(i&3)+8*(i>>2)+4*(lane>>5)
    const int col = cb * 32 + lc;
    int nz = 0;
#pragma unroll
    for (int m = 0; m < 2; ++m) {
#pragma unroll
      for (int i = 0; i < 16; ++i) {
        const int rl = m * 32 + (i & 3) + 8 * (i >> 2) + 4 * lh;
        const float sval = (m ? acc1[i] : acc0[i]) * rsc[rl];
        const float qv = rintf(sval * 20.0f) * 0.05f;
        nz |= (qv != 0.0f) ? 1 : 0;
      }
    }
    if (__ballot(nz != 0)) {  // rare: some sims crossed a bin boundary
#pragma unroll
      for (int m = 0; m < 2; ++m) {
#pragma unroll
        for (int i = 0; i < 16; ++i) {
          const int rl = m * 32 + (i & 3) + 8 * (i >> 2) + 4 * lh;
          const float sval = (m ? acc1[i] : acc0[i]) * rsc[rl];
          const float qv = rintf(sval * 20.0f) * 0.05f;
          if (qv != 0.0f) {
            const int idx = atomicAdd(g_np, 1);
            if (idx < CAPG) {
              g_pr[idx] = (unsigned int)(((rowbase + rl) << 10) | col);
              g_pq[idx] = qv;
            }
          }
        }
      }
    }
  }
}

// ---------------- fixup: scatter pairs into qsims and rewrite affected out
// rows exactly. No-op when np==0 (the expected case).
__global__ void fixup(const int* __restrict__ g_np,
                      const unsigned int* __restrict__ g_pr,
                      const float* __restrict__ g_pq,
                      const float* __restrict__ values,
                      const float* __restrict__ vsum, float* __restrict__ out,
                      float* __restrict__ qsims) {
  const int np = *g_np;
  if (np == 0 || np > CAPG) return;
  const int t = threadIdx.x;  // 256
  for (int p = t; p < np; p += 256) {
    const unsigned int pr = g_pr[p];
    qsims[(long)(pr >> 10) * NA + (pr & 1023)] = g_pq[p];
  }
  __syncthreads();
  const int h0 = t * 2;
  for (int p = 0; p < np; ++p) {
    const long row = (long)(g_pr[p] >> 10);
    float den = 1024.0f;
    float o0 = vsum[h0], o1 = vsum[h0 + 1];
    for (int p2 = 0; p2 < np; ++p2) {
      if ((long)(g_pr[p2] >> 10) == row) {
        const float dl = expf(g_pq[p2]) - 1.0f;
        den += dl;
        const float* vrow = values + (g_pr[p2] & 1023) * NH;
        o0 += dl * vrow[h0];
        o1 += dl * vrow[h0 + 1];
      }
    }
    out[row * NH + h0] = o0 / den;
    out[row * NH + h0 + 1] = o1 / den;
  }
}

// ---------------- safety net (never expected to run): dense recompute of
// qsims iff the pair list overflowed. Grid 2048, reads one int and exits.
__global__ void safety_qsims(const int* __restrict__ g_np,
                             const float* __restrict__ x,
                             const float* __restrict__ anchors,
                             float* __restrict__ qsims) {
  if (*g_np <= CAPG) return;
  const int t = threadIdx.x;  // 256
  __shared__ float xs[ND];
  __shared__ float xsc;
  for (int rr = 0; rr < 64; ++rr) {
    const long r = (long)blockIdx.x * 64 + rr;
    for (int d = t; d < ND; d += 256) xs[d] = x[r * ND + d];
    __syncthreads();
    if (t == 0) {
      float ss = 0.f;
      for (int d = 0; d < ND; ++d) ss += xs[d] * xs[d];
      xsc = (1.0f / sqrtf((float)ND)) / fmaxf(sqrtf(ss), 1e-12f);
    }
    __syncthreads();
    for (int a = t; a < NA; a += 256) {
      float dot = 0.f, an2 = 0.f;
      for (int d = 0; d < ND; ++d) {
        const float av = anchors[a * ND + d];
        dot += xs[d] * av;
        an2 += av * av;
      }
      const float sim = dot * xsc / fmaxf(sqrtf(an2), 1e-12f);
      qsims[r * NA + a] = rintf(sim * 20.0f) * 0.05f;
    }
    __syncthreads();
  }
}

__global__ void safety_out(const int* __restrict__ g_np,
                           const float* __restrict__ qsims,
                           const float* __restrict__ values,
                           float* __restrict__ out) {
  if (*g_np <= CAPG) return;
  const int t = threadIdx.x;  // 256
  __shared__ float e[NA];
  __shared__ float red[256];
  for (int rr = 0; rr < 64; ++rr) {
    const long r = (long)blockIdx.x * 64 + rr;
    float dl = 0.f;
    for (int a = t; a < NA; a += 256) {
      const float ev = expf(qsims[r * NA + a]);
      e[a] = ev;
      dl += ev;
    }
    red[t] = dl;
    __syncthreads();
    for (int s = 128; s; s >>= 1) {
      if (t < s) red[t] += red[t + s];
      __syncthreads();
    }
    const float inv = 1.0f / red[0];
    for (int h = t; h < NH; h += 256) {
      float o = 0.f;
      for (int a = 0; a < NA; ++a) o += e[a] * values[a * NH + h];
      out[r * NH + h] = o * inv;
    }
    __syncthreads();
  }
}

extern "C" void kernel_launch(void* const* d_in, const int* in_sizes, int n_in,
                              void* d_out, int out_size, void* d_ws,
                              size_t ws_size, hipStream_t stream) {
  (void)in_sizes; (void)n_in; (void)out_size; (void)ws_size;
  const float* x = (const float*)d_in[0];
  const float* anchors = (const float*)d_in[1];
  const float* values = (const float*)d_in[2];
  float* out = (float*)d_out;                        // [NB, NH]
  float* qsims = out + (size_t)NB * NH;              // [NB, NA]

  // workspace layout (<= 886848 bytes, matching the proven R1 budget)
  char* ws = (char*)d_ws;
  short* an_swz = (short*)ws;                                  // 768 KB
  float* vsum    = (float*)(ws + 786432);                      // 2 KB
  float* partial = (float*)(ws + 786432 + 2048);               // 64 KB
  int*   g_np    = (int*)(ws + 786432 + 2048 + 65536);         // 64 B slot
  unsigned int* g_pr = (unsigned int*)(ws + 786432 + 2048 + 65536 + 64);
  float* g_pq    = (float*)(ws + 786432 + 2048 + 65536 + 64 + 4 * CAPG);

  prep_anchors<<<NA, 64, 0, stream>>>(anchors, an_swz);
  vsum_part<<<32, 256, 0, stream>>>(values, partial);
  vsum_final<<<1, 512, 0, stream>>>(partial, vsum, g_np);
  mega<<<3584, 512, 0, stream>>>(x, an_swz, vsum, out, qsims, g_np, g_pr,
                                 g_pq);
  fixup<<<1, 256, 0, stream>>>(g_np, g_pr, g_pq, values, vsum, out, qsims);
  safety_qsims<<<2048, 256, 0, stream>>>(g_np, x, anchors, qsims);
  safety_out<<<2048, 256, 0, stream>>>(g_np, qsims, values, out);
}

// Round 9
// 256.409 us; speedup vs baseline: 3.8545x; 3.8545x over previous
//
#include <hip/hip_runtime.h>
#include <stdint.h>

// Problem constants (fixed by the reference's setup_inputs)
#define NB 131072
#define ND 384
#define NA 1024
#define NH 512
#define BM 64      // rows of x per block
#define CAP 256    // sparse correction-pair capacity per block

using f32x16 = __attribute__((ext_vector_type(16))) float;
using f32x4  = __attribute__((ext_vector_type(4))) float;

// pack 2 floats -> 2 fp8(e4m3,OCP on gfx950) bytes in 16 bits of old
__device__ __forceinline__ unsigned char f2fp8(float f) {
  return (unsigned char)(__builtin_amdgcn_cvt_pk_fp8_f32(f, 0.f, 0, false) &
                         0xff);
}

// ---------------- prep: normalize anchors -> fp8, MFMA B-fragment order for
// v_mfma_f32_32x32x16_fp8_fp8 (8 fp8/lane, K=16):
//   lane l holds B[k = s*16 + (l>>5)*8 + j][col = cb*32 + (l&31)], j=0..7
// byte address: (cb*24+s)*512 + l*8 + j  -> wave step-load = 512 B contiguous.
__global__ void prep_anchors(const float* __restrict__ anchors,
                             unsigned char* __restrict__ an8) {
  const int a = blockIdx.x;    // anchor row
  const int l = threadIdx.x;   // 64 lanes
  float v[6];
  float ss = 0.f;
#pragma unroll
  for (int e = 0; e < 6; ++e) {
    v[e] = anchors[a * ND + l + 64 * e];
    ss += v[e] * v[e];
  }
#pragma unroll
  for (int off = 32; off >= 1; off >>= 1) ss += __shfl_xor(ss, off);
  const float rn = 1.0f / fmaxf(sqrtf(ss), 1e-12f);
  const int cb = a >> 5;
#pragma unroll
  for (int e = 0; e < 6; ++e) {
    const int k = l + 64 * e;
    const int s = k >> 4, half = (k >> 3) & 1, j = k & 7;
    const int l2 = (a & 31) + 32 * half;
    an8[(size_t)(cb * 24 + s) * 512 + l2 * 8 + j] = f2fp8(v[e] * rn);
  }
}

// ---------------- prep: Vsum[h] = sum_a values[a][h] (two-stage, deterministic)
__global__ void vsum_part(const float* __restrict__ values,
                          float* __restrict__ partial) {
  const int jb = blockIdx.x, t = threadIdx.x;
  for (int hh = t; hh < NH; hh += 256) {
    float s = 0.f;
    for (int a2 = 0; a2 < 32; ++a2) s += values[(jb * 32 + a2) * NH + hh];
    partial[jb * NH + hh] = s;
  }
}

__global__ void vsum_final(const float* __restrict__ partial,
                           float* __restrict__ vsum) {
  const int t = threadIdx.x;
  float s = 0.f;
  for (int j = 0; j < 32; ++j) s += partial[j * NH + t];
  vsum[t] = s;
}

// ---------------- main fused kernel — R1's proven structure, fp8 operands.
// grid = NB/BM blocks, 512 threads (8 waves). Wave w owns anchor block
// cb = chunk*8 + w (4 chunks); computes BOTH 32-row halves per B load.
// xbuf fp8 [64][384] (24 KB), XOR-swizzle (r&15)<<3 on byte offset ->
// A ds_read_b64 is ~2-way on banks (free). B = 512 B/step wave load from a
// 384 KB L2-resident panel. Dense qsims stores in-kernel; out in epilogue.
__global__ __launch_bounds__(512, 6) void fused_main(
    const float* __restrict__ x, const unsigned char* __restrict__ an8,
    const float* __restrict__ values, const float* __restrict__ vsum,
    float* __restrict__ out, float* __restrict__ qsims) {
  __shared__ unsigned char xbuf[BM * 384];  // fp8 [64][384], XOR-swizzled
  __shared__ float rsc[BM];
  __shared__ float vsum_s[NH];
  __shared__ float denom_add[BM];
  __shared__ int npairs;
  __shared__ int pr_ra[CAP];
  __shared__ float pr_d[CAP];

  const int t = threadIdx.x;
  const long rowbase = (long)blockIdx.x * BM;

  if (t < BM) denom_add[t] = 0.f;
  if (t == 0) npairs = 0;
  vsum_s[t] = vsum[t];

  // ---- stage x tile fp32 -> fp8 (coalesced reads, 8B LDS chunks)
  {
    const int r = t >> 3, c = t & 7;  // 8 threads per row
    const float* xrow = x + (rowbase + r) * ND;
    float ss = 0.f;
#pragma unroll
    for (int j = 0; j < 6; ++j) {
      const int col0 = c * 8 + j * 64;
      f32x4 v0 = *reinterpret_cast<const f32x4*>(xrow + col0);
      f32x4 v1 = *reinterpret_cast<const f32x4*>(xrow + col0 + 4);
      ss += v0[0] * v0[0] + v0[1] * v0[1] + v0[2] * v0[2] + v0[3] * v0[3];
      ss += v1[0] * v1[0] + v1[1] * v1[1] + v1[2] * v1[2] + v1[3] * v1[3];
      int lo = __builtin_amdgcn_cvt_pk_fp8_f32(v0[0], v0[1], 0, false);
      lo = __builtin_amdgcn_cvt_pk_fp8_f32(v0[2], v0[3], lo, true);
      int hi = __builtin_amdgcn_cvt_pk_fp8_f32(v1[0], v1[1], 0, false);
      hi = __builtin_amdgcn_cvt_pk_fp8_f32(v1[2], v1[3], hi, true);
      const long pk = ((long)(unsigned)lo) | ((long)hi << 32);
      // r*384 is a multiple of 128 -> XOR on bits 3..6 stays within the row;
      // col0 is a multiple of 8 -> 8B chunks preserved under the XOR.
      *reinterpret_cast<long*>(
          xbuf + r * 384 + (col0 ^ ((r & 15) << 3))) = pk;
    }
    ss += __shfl_xor(ss, 1);
    ss += __shfl_xor(ss, 2);
    ss += __shfl_xor(ss, 4);
    if (c == 0) {
      const float scale = 1.0f / sqrtf((float)ND);
      rsc[r] = scale / fmaxf(sqrtf(ss), 1e-12f);
    }
  }
  __syncthreads();

  const int w = t >> 6, l = t & 63;
  const int lc = l & 31, lh = l >> 5;
  const int swz = (lc & 15) << 3;
  const unsigned char* arow0 = xbuf + 384 * lc;
  const unsigned char* arow1 = xbuf + 384 * (lc + 32);

  for (int chunk = 0; chunk < 4; ++chunk) {
    const int cb = chunk * 8 + w;  // global 32-col anchor block, 0..31
    f32x16 acc0 = {0, 0, 0, 0, 0, 0, 0, 0, 0, 0, 0, 0, 0, 0, 0, 0};
    f32x16 acc1 = {0, 0, 0, 0, 0, 0, 0, 0, 0, 0, 0, 0, 0, 0, 0, 0};
    const unsigned char* bptr = an8 + (size_t)(cb * 24) * 512 + l * 8;
#pragma unroll
    for (int s = 0; s < 24; ++s) {
      const int off = (s * 16 + lh * 8) ^ swz;
      const long a0 = *reinterpret_cast<const long*>(arow0 + off);
      const long a1 = *reinterpret_cast<const long*>(arow1 + off);
      const long bb = *reinterpret_cast<const long*>(bptr + s * 512);
      acc0 = __builtin_amdgcn_mfma_f32_32x32x16_fp8_fp8(a0, bb, acc0, 0, 0, 0);
      acc1 = __builtin_amdgcn_mfma_f32_32x32x16_fp8_fp8(a1, bb, acc1, 0, 0, 0);
    }

    // quantize + write qsims; C/D layout: col=lane&31, row=(i&3)+8*(i>>2)+4*(lane>>5)
    const int col = cb * 32 + lc;
    int nz = 0;
#pragma unroll
    for (int m = 0; m < 2; ++m) {
#pragma unroll
      for (int i = 0; i < 16; ++i) {
        const int rl = m * 32 + (i & 3) + 8 * (i >> 2) + 4 * lh;
        const float sval = (m ? acc1[i] : acc0[i]) * rsc[rl];
        const float qv = rintf(sval * 20.0f) * 0.05f;
        qsims[(rowbase + rl) * NA + col] = qv;
        nz |= (qv != 0.0f) ? 1 : 0;
      }
    }
    if (__ballot(nz != 0)) {  // rare: some sims crossed a bin boundary
#pragma unroll
      for (int m = 0; m < 2; ++m) {
#pragma unroll
        for (int i = 0; i < 16; ++i) {
          const int rl = m * 32 + (i & 3) + 8 * (i >> 2) + 4 * lh;
          const float sval = (m ? acc1[i] : acc0[i]) * rsc[rl];
          const float qv = rintf(sval * 20.0f) * 0.05f;
          if (qv != 0.0f) {
            const float dl = expf(qv) - 1.0f;
            const int idx = atomicAdd(&npairs, 1);
            if (idx < CAP) {
              pr_ra[idx] = (rl << 16) | col;
              pr_d[idx] = dl;
            }
            atomicAdd(&denom_add[rl], dl);
          }
        }
      }
    }
  }
  __syncthreads();

  // ---- epilogue: output rows
  const int np = npairs;
  const int hq = (t & 127) * 4;
  const int rb = t >> 7;
  if (np <= CAP) {
    for (int it = 0; it < 16; ++it) {
      const int r = it * 4 + rb;
      const float inv = 1.0f / (1024.0f + denom_add[r]);
      f32x4 o = *reinterpret_cast<const f32x4*>(&vsum_s[hq]);
      for (int p = 0; p < np; ++p) {
        const int ra = pr_ra[p];
        if ((ra >> 16) == r) {
          const float dl = pr_d[p];
          const float* vrow = values + (ra & 0xffff) * NH + hq;
          o[0] += dl * vrow[0];
          o[1] += dl * vrow[1];
          o[2] += dl * vrow[2];
          o[3] += dl * vrow[3];
        }
      }
      o[0] *= inv; o[1] *= inv; o[2] *= inv; o[3] *= inv;
      *reinterpret_cast<f32x4*>(out + (rowbase + r) * NH + hq) = o;
    }
  } else {
    // fully-general fallback (never expected): recompute from qsims
    for (int it = 0; it < 16; ++it) {
      const int r = it * 4 + rb;
      const float* qrow = qsims + (rowbase + r) * NA;
      float den = 0.f;
      f32x4 o = {0.f, 0.f, 0.f, 0.f};
      for (int a = 0; a < NA; ++a) {
        const float e = expf(qrow[a]);
        den += e;
        const float* vrow = values + a * NH + hq;
        o[0] += e * vrow[0];
        o[1] += e * vrow[1];
        o[2] += e * vrow[2];
        o[3] += e * vrow[3];
      }
      const float inv = 1.0f / den;
      o[0] *= inv; o[1] *= inv; o[2] *= inv; o[3] *= inv;
      *reinterpret_cast<f32x4*>(out + (rowbase + r) * NH + hq) = o;
    }
  }
}

extern "C" void kernel_launch(void* const* d_in, const int* in_sizes, int n_in,
                              void* d_out, int out_size, void* d_ws,
                              size_t ws_size, hipStream_t stream) {
  (void)in_sizes; (void)n_in; (void)out_size; (void)ws_size;
  const float* x = (const float*)d_in[0];
  const float* anchors = (const float*)d_in[1];
  const float* values = (const float*)d_in[2];
  float* out = (float*)d_out;                        // [NB, NH]
  float* qsims = out + (size_t)NB * NH;              // [NB, NA]

  // workspace layout
  char* ws = (char*)d_ws;
  unsigned char* an8 = (unsigned char*)ws;           // 384 KB
  float* vsum    = (float*)(ws + 393216);            // 2 KB
  float* partial = (float*)(ws + 393216 + 2048);     // 64 KB

  prep_anchors<<<NA, 64, 0, stream>>>(anchors, an8);
  vsum_part<<<32, 256, 0, stream>>>(values, partial);
  vsum_final<<<1, 512, 0, stream>>>(partial, vsum);
  fused_main<<<NB / BM, 512, 0, stream>>>(x, an8, values, vsum, out, qsims);
}